// Round 3
// baseline (97.485 us; speedup 1.0000x reference)
//
#include <hip/hip_runtime.h>

#define B_ 16
#define A_ 3
#define G_ 76
#define GG_ (G_*G_)             // 5776
#define NC_ 80
#define C_ 85
#define NCELL (B_*A_*GG_)       // 277248
#define NBLK (B_*A_*G_)         // 3648
#define NV4 (C_*19)             // 1615 float4 per tile
#define NIT 7                   // ceil(1615/256)
#define OUTN ((size_t)NCELL*C_) // 23566080

typedef float f4 __attribute__((ext_vector_type(4)));

__device__ __forceinline__ float sigf(float v){ return 1.0f/(1.0f + __expf(-v)); }
__device__ __forceinline__ float clog_(float p){ return fmaxf(__logf(p), -100.0f); }
__device__ __forceinline__ float bcef(float p, float t){ return -(t*clog_(p) + (1.0f-t)*clog_(1.0f-p)); }

// ---------------- mask dtype detection ----------------
__global__ __launch_bounds__(256) void detect_kernel(const unsigned int* __restrict__ m,
                                                     unsigned int* __restrict__ flags){
    unsigned idx = blockIdx.x*256u + threadIdx.x;
    unsigned v = (idx < (NCELL/4)) ? m[idx] : 0u;
    int n01 = (v > 1u);
    int nfl = (v != 0u) && (v != 0x3F800000u);
    if (__any(n01) && (threadIdx.x & 63) == 0) atomicOr(&flags[0], 1u);
    if (__any(nfl) && (threadIdx.x & 63) == 0) atomicOr(&flags[1], 1u);
}

// ---------------- fused transpose+transform+loss ----------------
__global__ __launch_bounds__(256) void fused_kernel(
        const float* __restrict__ x, const float* __restrict__ iou,
        const void* __restrict__ om, const void* __restrict__ nm,
        const float* __restrict__ tw, const float* __restrict__ th,
        const float* __restrict__ tcls, const float* __restrict__ tconf,
        const float* __restrict__ tbox, const unsigned int* __restrict__ flags,
        float* __restrict__ out, float* __restrict__ partials){
    __shared__ __align__(16) float ot[G_*C_];   // [m][k] output-layout tile
    __shared__ float raww[2][G_];               // raw pw, ph
    __shared__ float sm[6][4];

    // XCD-aware swizzle: consecutive logical blocks on one XCD (NBLK%8==0)
    int blk = ((int)blockIdx.x & 7)*(NBLK/8) + ((int)blockIdx.x >> 3);
    int i  = blk % G_;
    int ba = blk / G_;
    int a  = ba % A_;
    const float* base = x + (size_t)ba*C_*GG_ + (size_t)i*G_;

    // ---- phase 1a: issue all tile loads (7 independent float4 in flight) ----
    f4 v[NIT];
    #pragma unroll
    for (int u=0;u<NIT;u++){
        int idx = (int)threadIdx.x + u*256;
        if (idx < NV4){
            int k  = idx/19;
            int j4 = idx - k*19;
            v[u] = *(const f4*)(base + (size_t)k*GG_ + j4*4);
        }
    }

    // ---- phase 3a: issue small-tensor loads early (overlap with phase 1) ----
    const bool act = threadIdx.x < G_;
    int j = (int)threadIdx.x;
    size_t n = (size_t)ba*GG_ + (size_t)i*G_ + (size_t)j;
    int mode = (flags[0]==0u) ? 0 : ((flags[1]==0u) ? 1 : 2);
    bool obj=false, noobj=false;
    float tcf=0.f, iouv=0.f, twv=1.f, thv=1.f;
    if (act){
        if (mode == 2){
            obj   = ((const unsigned char*)om)[n] != 0;
            noobj = ((const unsigned char*)nm)[n] != 0;
        } else {
            obj   = ((const unsigned int*)om)[n] != 0u;   // works for int32 and f32 bitpattern
            noobj = ((const unsigned int*)nm)[n] != 0u;
        }
        tcf  = tconf[n];
        iouv = iou[n];
        twv  = tw[n];
        thv  = th[n];
    }

    // ---- phase 1b: transform + transposed LDS writes ----
    float aw8 = (a==0)?12.0f:((a==1)?19.0f:40.0f);
    float ah8 = (a==0)?16.0f:((a==1)?36.0f:28.0f);
    float fi = (float)i;
    #pragma unroll
    for (int u=0;u<NIT;u++){
        int idx = (int)threadIdx.x + u*256;
        if (idx < NV4){
            int k  = idx/19;
            int j4 = idx - k*19;
            int m0 = j4*4;
            float e0=v[u][0], e1=v[u][1], e2=v[u][2], e3=v[u][3];
            float r0,r1,r2,r3;
            if (k >= 4){
                r0=sigf(e0); r1=sigf(e1); r2=sigf(e2); r3=sigf(e3);
            } else if (k == 0){
                r0=(sigf(e0)+(float)(m0+0))*8.0f; r1=(sigf(e1)+(float)(m0+1))*8.0f;
                r2=(sigf(e2)+(float)(m0+2))*8.0f; r3=(sigf(e3)+(float)(m0+3))*8.0f;
            } else if (k == 1){
                r0=(sigf(e0)+fi)*8.0f; r1=(sigf(e1)+fi)*8.0f;
                r2=(sigf(e2)+fi)*8.0f; r3=(sigf(e3)+fi)*8.0f;
            } else if (k == 2){
                r0=__expf(e0)*aw8; r1=__expf(e1)*aw8; r2=__expf(e2)*aw8; r3=__expf(e3)*aw8;
                raww[0][m0+0]=e0; raww[0][m0+1]=e1; raww[0][m0+2]=e2; raww[0][m0+3]=e3;
            } else {
                r0=__expf(e0)*ah8; r1=__expf(e1)*ah8; r2=__expf(e2)*ah8; r3=__expf(e3)*ah8;
                raww[1][m0+0]=e0; raww[1][m0+1]=e1; raww[1][m0+2]=e2; raww[1][m0+3]=e3;
            }
            ot[(m0+0)*C_ + k] = r0;
            ot[(m0+1)*C_ + k] = r1;
            ot[(m0+2)*C_ + k] = r2;
            ot[(m0+3)*C_ + k] = r3;
        }
    }
    __syncthreads();

    // ---- phase 2: register-staged float4 copy-out (coalesced, nontemporal) ----
    {
        f4 r[NIT];
        const f4* src4 = (const f4*)ot;
        #pragma unroll
        for (int u=0;u<NIT;u++){
            int idx = (int)threadIdx.x + u*256;
            if (idx < NV4) r[u] = src4[idx];
        }
        f4* dst4 = (f4*)(out + (size_t)blk*(G_*C_));
        #pragma unroll
        for (int u=0;u<NIT;u++){
            int idx = (int)threadIdx.x + u*256;
            if (idx < NV4) __builtin_nontemporal_store(r[u], dst4 + idx);
        }
    }

    // ---- phase 3b: loss compute (overlaps store drain) ----
    float s0=0.f, s1=0.f, s2=0.f, s3=0.f;
    if (act && (obj || noobj)){
        float pconf = ot[j*C_ + 4];
        float bc = bcef(pconf, tcf);
        if (noobj) s2 = bc;
        if (obj){
            s1 = bc;
            float bx = ot[j*C_+0]*0.125f;
            float by = ot[j*C_+1]*0.125f;
            float bw = ot[j*C_+2]*0.125f;
            float bh = ot[j*C_+3]*0.125f;
            float pwv = raww[0][j], phv = raww[1][j];
            f4 tb = *(const f4*)(tbox + n*4);
            float txc=tb[0], tyc=tb[1], twd=tb[2], tht=tb[3];
            float tx1 = txc - twd*0.5f, ty1 = tyc - tht*0.5f;
            float tx2 = txc + twd*0.5f, ty2 = tyc + tht*0.5f;
            float px1 = bx - bw*0.5f,  py1 = by - bh*0.5f;
            float px2 = bx + bw*0.5f,  py2 = by + bh*0.5f;
            float xc1 = fminf(px1, tx1), yc1 = fminf(py1, ty1);
            float xc2 = fmaxf(px2, tx2), yc2 = fmaxf(py2, ty2);
            float cc = (xc2-xc1)*(xc2-xc1) + (yc2-yc1)*(yc2-yc1) + 1e-7f;
            float dd = (txc-bx)*(txc-bx) + (tyc-by)*(tyc-by);
            float rdiou = dd/cc;
            float dat = atanf(twv/thv) - atanf(pwv/phv);
            float vv = 0.40528473456935108577f * dat*dat;
            float Si = 1.0f - iouv;
            float alpha = vv/(Si+vv);
            s0 = 1.0f - iouv + rdiou + alpha*vv;
            const float* tcl = tcls + n*NC_;
            float cls = 0.f;
            #pragma unroll 4
            for (int c=0;c<NC_;c++)
                cls += bcef(ot[j*C_+5+c], tcl[c]);
            s3 = cls;
        }
    }

    // ---- reduction: ballot counts + 4 shfl chains ----
    unsigned long long bo  = __ballot(act && obj);
    unsigned long long bn2 = __ballot(act && noobj);
    float vals[4] = {s0, s1, s2, s3};
    #pragma unroll
    for (int q=0;q<4;q++){
        float vv2 = vals[q];
        #pragma unroll
        for (int o=32;o>0;o>>=1) vv2 += __shfl_xor(vv2, o, 64);
        vals[q] = vv2;
    }
    int lane = threadIdx.x & 63, wid = (int)threadIdx.x >> 6;
    if (lane == 0){
        sm[0][wid] = vals[0]; sm[1][wid] = vals[1];
        sm[2][wid] = vals[2]; sm[3][wid] = vals[3];
        sm[4][wid] = (float)__popcll(bo);
        sm[5][wid] = (float)__popcll(bn2);
    }
    __syncthreads();
    if (threadIdx.x == 0){
        #pragma unroll
        for (int q=0;q<6;q++)
            partials[(size_t)q*NBLK + blk] = sm[q][0]+sm[q][1]+sm[q][2]+sm[q][3];
    }
}

// ---------------- final reduction ----------------
__global__ __launch_bounds__(256) void final_kernel(const float* __restrict__ partials,
                                                    float* __restrict__ out_loss){
    double acc[6] = {0,0,0,0,0,0};
    for (int idx = (int)threadIdx.x; idx < NBLK; idx += 256){
        #pragma unroll
        for (int q=0;q<6;q++) acc[q] += (double)partials[(size_t)q*NBLK + idx];
    }
    #pragma unroll
    for (int q=0;q<6;q++){
        double v = acc[q];
        #pragma unroll
        for (int o=32;o>0;o>>=1) v += __shfl_xor(v, o, 64);
        acc[q] = v;
    }
    __shared__ double smd[6][4];
    int lane = threadIdx.x & 63, wid = (int)threadIdx.x >> 6;
    if (lane == 0){
        #pragma unroll
        for (int q=0;q<6;q++) smd[q][wid] = acc[q];
    }
    __syncthreads();
    if (threadIdx.x == 0){
        double s[6];
        #pragma unroll
        for (int q=0;q<6;q++) s[q] = smd[q][0]+smd[q][1]+smd[q][2]+smd[q][3];
        double cnt_o = fmax(s[4], 1.0);
        double cnt_n = fmax(s[5], 1.0);
        double total = s[0]/(double)B_
                     + s[1]/cnt_o
                     + 100.0*s[2]/cnt_n
                     + s[3]/(cnt_o*(double)NC_);
        *out_loss = (float)total;
    }
}

extern "C" void kernel_launch(void* const* d_in, const int* in_sizes, int n_in,
                              void* d_out, int out_size, void* d_ws, size_t ws_size,
                              hipStream_t stream){
    const float* x     = (const float*)d_in[0];
    const float* iou   = (const float*)d_in[1];
    const void*  om    = d_in[2];
    const void*  nm    = d_in[3];
    const float* tw    = (const float*)d_in[4];
    const float* th    = (const float*)d_in[5];
    const float* tcls  = (const float*)d_in[6];
    const float* tconf = (const float*)d_in[7];
    const float* tbox  = (const float*)d_in[8];
    float* out = (float*)d_out;

    unsigned int* flags = (unsigned int*)d_ws;
    float* partials = (float*)((char*)d_ws + 64);

    hipMemsetAsync(d_ws, 0, 64, stream);
    detect_kernel<<<(NCELL/4 + 255)/256, 256, 0, stream>>>((const unsigned int*)om, flags);
    fused_kernel<<<NBLK, 256, 0, stream>>>(x, iou, om, nm, tw, th, tcls, tconf, tbox,
                                           flags, out, partials);
    final_kernel<<<1, 256, 0, stream>>>(partials, out + OUTN);
}

// Round 4
// 82.139 us; speedup vs baseline: 1.1868x; 1.1868x over previous
//
#include <hip/hip_runtime.h>

#define B_ 16
#define A_ 3
#define G_ 76
#define GG_ (G_*G_)             // 5776
#define NC_ 80
#define C_ 85
#define NCELL (B_*A_*GG_)       // 277248
#define NBLK (B_*A_*G_)         // 3648
#define NV4 (C_*19)             // 1615 float4 per tile
#define NIT 7                   // ceil(1615/256)
#define OUTN ((size_t)NCELL*C_) // 23566080

typedef float f4 __attribute__((ext_vector_type(4)));

__device__ __forceinline__ float sigf(float v){ return 1.0f/(1.0f + __expf(-v)); }
__device__ __forceinline__ float clog_(float p){ return fmaxf(__logf(p), -100.0f); }
__device__ __forceinline__ float bcef(float p, float t){ return -(t*clog_(p) + (1.0f-t)*clog_(1.0f-p)); }

// async global->LDS, 16B per lane; LDS dest must be wave-uniform base + lane*16
__device__ __forceinline__ void cp16(const float* g, float* l){
    __builtin_amdgcn_global_load_lds((const __attribute__((address_space(1))) void*)g,
                                     (__attribute__((address_space(3))) void*)l,
                                     16, 0, 0);
}

// ---------------- mask dtype detection (1 block, scans dense noobj mask) ----------------
__global__ __launch_bounds__(256) void detect_kernel(const unsigned int* __restrict__ nm,
                                                     unsigned int* __restrict__ flags){
    unsigned a01 = 0, afl = 0;
    for (int idx = (int)threadIdx.x; idx < 4096; idx += 256){
        unsigned v = nm[idx];
        a01 |= (v > 1u) ? 1u : 0u;                              // not int32 {0,1}
        afl |= ((v != 0u) && (v != 0x3F800000u)) ? 1u : 0u;     // not f32 {0,1.0}
    }
    if (a01) atomicOr(&flags[0], 1u);
    if (afl) atomicOr(&flags[1], 1u);
}

// ---------------- fused transpose+transform+loss ----------------
__global__ __launch_bounds__(256, 6) void fused_kernel(
        const float* __restrict__ x, const float* __restrict__ iou,
        const void* __restrict__ om, const void* __restrict__ nm,
        const float* __restrict__ tw, const float* __restrict__ th,
        const float* __restrict__ tcls, const float* __restrict__ tconf,
        const float* __restrict__ tbox, const unsigned int* __restrict__ flags,
        float* __restrict__ out, float* __restrict__ partials){
    __shared__ __align__(16) float ot[G_*C_];   // raw tile (linear), then transformed [m][k]
    __shared__ float raww[2][G_];               // raw pw, ph
    __shared__ float sm[6][4];

    const int tid = (int)threadIdx.x;
    // XCD-aware swizzle (NBLK % 8 == 0): contiguous logical rows per XCD
    int blk = ((int)blockIdx.x & 7)*(NBLK/8) + ((int)blockIdx.x >> 3);
    int i  = blk % G_;
    int ba = blk / G_;
    int a  = ba % A_;
    const float* base = x + (size_t)ba*C_*GG_ + (size_t)i*G_;

    // ---- phase 1a: async-load raw tile into LDS (no VGPRs held) ----
    #pragma unroll
    for (int u=0;u<NIT;u++){
        int idx = tid + u*256;
        if (idx < NV4){
            int k  = idx/19;
            int j4 = idx - k*19;
            cp16(base + (size_t)k*GG_ + j4*4, ot + (size_t)idx*4);
        }
    }

    // ---- phase 3a: issue tiny per-cell loads early (5 dwords, 76 threads) ----
    const bool act = tid < G_;
    int j = tid;
    size_t n = (size_t)ba*GG_ + (size_t)i*G_ + (size_t)j;
    int mode = (flags[0]==0u) ? 0 : ((flags[1]==0u) ? 1 : 2);
    bool obj=false, noobj=false;
    float tcf=0.f, iouv=0.f, twv=1.f, thv=1.f;
    if (act){
        if (mode == 2){
            obj   = ((const unsigned char*)om)[n] != 0;
            noobj = ((const unsigned char*)nm)[n] != 0;
        } else {
            obj   = ((const unsigned int*)om)[n] != 0u;   // int32 or f32 bitpattern
            noobj = ((const unsigned int*)nm)[n] != 0u;
        }
        tcf  = tconf[n];
        iouv = iou[n];
        twv  = tw[n];
        thv  = th[n];
    }

    __syncthreads();   // drains vmcnt: raw tile resident

    // ---- phase 1b: read own 7 f4 from LDS ----
    f4 r[NIT];
    #pragma unroll
    for (int u=0;u<NIT;u++){
        int idx = tid + u*256;
        if (idx < NV4) r[u] = ((const f4*)ot)[idx];
    }
    __syncthreads();   // all raw reads done before transposed overwrite

    // ---- phase 1c: transform + transposed write (in-place) ----
    float aw8 = (a==0)?12.0f:((a==1)?19.0f:40.0f);
    float ah8 = (a==0)?16.0f:((a==1)?36.0f:28.0f);
    float fi = (float)i;
    #pragma unroll
    for (int u=0;u<NIT;u++){
        int idx = tid + u*256;
        if (idx < NV4){
            int k  = idx/19;
            int j4 = idx - k*19;
            int m0 = j4*4;
            float e0=r[u][0], e1=r[u][1], e2=r[u][2], e3=r[u][3];
            float r0,r1,r2,r3;
            if (k >= 4){
                r0=sigf(e0); r1=sigf(e1); r2=sigf(e2); r3=sigf(e3);
            } else if (k == 0){
                r0=(sigf(e0)+(float)(m0+0))*8.0f; r1=(sigf(e1)+(float)(m0+1))*8.0f;
                r2=(sigf(e2)+(float)(m0+2))*8.0f; r3=(sigf(e3)+(float)(m0+3))*8.0f;
            } else if (k == 1){
                r0=(sigf(e0)+fi)*8.0f; r1=(sigf(e1)+fi)*8.0f;
                r2=(sigf(e2)+fi)*8.0f; r3=(sigf(e3)+fi)*8.0f;
            } else if (k == 2){
                r0=__expf(e0)*aw8; r1=__expf(e1)*aw8; r2=__expf(e2)*aw8; r3=__expf(e3)*aw8;
                raww[0][m0+0]=e0; raww[0][m0+1]=e1; raww[0][m0+2]=e2; raww[0][m0+3]=e3;
            } else {
                r0=__expf(e0)*ah8; r1=__expf(e1)*ah8; r2=__expf(e2)*ah8; r3=__expf(e3)*ah8;
                raww[1][m0+0]=e0; raww[1][m0+1]=e1; raww[1][m0+2]=e2; raww[1][m0+3]=e3;
            }
            ot[(m0+0)*C_ + k] = r0;
            ot[(m0+1)*C_ + k] = r1;
            ot[(m0+2)*C_ + k] = r2;
            ot[(m0+3)*C_ + k] = r3;
        }
    }
    __syncthreads();

    // ---- phase 2: copy-out (ds_read b128 + plain coalesced stores) ----
    {
        const f4* src4 = (const f4*)ot;
        f4* dst4 = (f4*)(out + (size_t)blk*(G_*C_));
        #pragma unroll
        for (int u=0;u<NIT;u++){
            int idx = tid + u*256;
            if (idx < NV4) r[u] = src4[idx];
        }
        #pragma unroll
        for (int u=0;u<NIT;u++){
            int idx = tid + u*256;
            if (idx < NV4) dst4[idx] = r[u];
        }
    }

    // ---- phase 3b: loss compute (overlaps store drain) ----
    float s0=0.f, s1=0.f, s2=0.f, s3=0.f;
    if (act && (obj || noobj)){
        float pconf = ot[j*C_ + 4];
        float bc = bcef(pconf, tcf);
        if (noobj) s2 = bc;
        if (obj){
            s1 = bc;
            float bx = ot[j*C_+0]*0.125f;
            float by = ot[j*C_+1]*0.125f;
            float bw = ot[j*C_+2]*0.125f;
            float bh = ot[j*C_+3]*0.125f;
            float pwv = raww[0][j], phv = raww[1][j];
            f4 tb = *(const f4*)(tbox + n*4);
            float txc=tb[0], tyc=tb[1], twd=tb[2], tht=tb[3];
            float tx1 = txc - twd*0.5f, ty1 = tyc - tht*0.5f;
            float tx2 = txc + twd*0.5f, ty2 = tyc + tht*0.5f;
            float px1 = bx - bw*0.5f,  py1 = by - bh*0.5f;
            float px2 = bx + bw*0.5f,  py2 = by + bh*0.5f;
            float xc1 = fminf(px1, tx1), yc1 = fminf(py1, ty1);
            float xc2 = fmaxf(px2, tx2), yc2 = fmaxf(py2, ty2);
            float cc = (xc2-xc1)*(xc2-xc1) + (yc2-yc1)*(yc2-yc1) + 1e-7f;
            float dd = (txc-bx)*(txc-bx) + (tyc-by)*(tyc-by);
            float rdiou = dd/cc;
            float dat = atanf(twv/thv) - atanf(pwv/phv);
            float vv = 0.40528473456935108577f * dat*dat;
            float Si = 1.0f - iouv;
            float alpha = vv/(Si+vv);
            s0 = 1.0f - iouv + rdiou + alpha*vv;
            const float* tcl = tcls + n*NC_;
            float cls = 0.f;
            #pragma unroll 4
            for (int c=0;c<NC_;c++)
                cls += bcef(ot[j*C_+5+c], tcl[c]);
            s3 = cls;
        }
    }

    // ---- reduction: ballot counts + 4 shfl chains ----
    unsigned long long bo  = __ballot(act && obj);
    unsigned long long bn2 = __ballot(act && noobj);
    float vals[4] = {s0, s1, s2, s3};
    #pragma unroll
    for (int q=0;q<4;q++){
        float vv2 = vals[q];
        #pragma unroll
        for (int o=32;o>0;o>>=1) vv2 += __shfl_xor(vv2, o, 64);
        vals[q] = vv2;
    }
    int lane = tid & 63, wid = tid >> 6;
    if (lane == 0){
        sm[0][wid] = vals[0]; sm[1][wid] = vals[1];
        sm[2][wid] = vals[2]; sm[3][wid] = vals[3];
        sm[4][wid] = (float)__popcll(bo);
        sm[5][wid] = (float)__popcll(bn2);
    }
    __syncthreads();
    if (tid == 0){
        #pragma unroll
        for (int q=0;q<6;q++)
            partials[(size_t)q*NBLK + blk] = sm[q][0]+sm[q][1]+sm[q][2]+sm[q][3];
    }
}

// ---------------- final reduction ----------------
__global__ __launch_bounds__(256) void final_kernel(const float* __restrict__ partials,
                                                    float* __restrict__ out_loss){
    double acc[6] = {0,0,0,0,0,0};
    for (int idx = (int)threadIdx.x; idx < NBLK; idx += 256){
        #pragma unroll
        for (int q=0;q<6;q++) acc[q] += (double)partials[(size_t)q*NBLK + idx];
    }
    #pragma unroll
    for (int q=0;q<6;q++){
        double v = acc[q];
        #pragma unroll
        for (int o=32;o>0;o>>=1) v += __shfl_xor(v, o, 64);
        acc[q] = v;
    }
    __shared__ double smd[6][4];
    int lane = threadIdx.x & 63, wid = (int)threadIdx.x >> 6;
    if (lane == 0){
        #pragma unroll
        for (int q=0;q<6;q++) smd[q][wid] = acc[q];
    }
    __syncthreads();
    if (threadIdx.x == 0){
        double s[6];
        #pragma unroll
        for (int q=0;q<6;q++) s[q] = smd[q][0]+smd[q][1]+smd[q][2]+smd[q][3];
        double cnt_o = fmax(s[4], 1.0);
        double cnt_n = fmax(s[5], 1.0);
        double total = s[0]/(double)B_
                     + s[1]/cnt_o
                     + 100.0*s[2]/cnt_n
                     + s[3]/(cnt_o*(double)NC_);
        *out_loss = (float)total;
    }
}

extern "C" void kernel_launch(void* const* d_in, const int* in_sizes, int n_in,
                              void* d_out, int out_size, void* d_ws, size_t ws_size,
                              hipStream_t stream){
    const float* x     = (const float*)d_in[0];
    const float* iou   = (const float*)d_in[1];
    const void*  om    = d_in[2];
    const void*  nm    = d_in[3];
    const float* tw    = (const float*)d_in[4];
    const float* th    = (const float*)d_in[5];
    const float* tcls  = (const float*)d_in[6];
    const float* tconf = (const float*)d_in[7];
    const float* tbox  = (const float*)d_in[8];
    float* out = (float*)d_out;

    unsigned int* flags = (unsigned int*)d_ws;
    float* partials = (float*)((char*)d_ws + 64);

    hipMemsetAsync(d_ws, 0, 64, stream);
    detect_kernel<<<1, 256, 0, stream>>>((const unsigned int*)nm, flags);
    fused_kernel<<<NBLK, 256, 0, stream>>>(x, iou, om, nm, tw, th, tcls, tconf, tbox,
                                           flags, out, partials);
    final_kernel<<<1, 256, 0, stream>>>(partials, out + OUTN);
}